// Round 1
// baseline (1355.022 us; speedup 1.0000x reference)
//
#include <hip/hip_runtime.h>

// One workgroup (512 thr) per group n (1024 groups of 16ch x 64x64).
// v2: latency-bound fix. Drop the 139KB full-image LDS (was 1 block/CU).
// Conv runs on 4 staged 16-row bf16 chunks (18-row halo buffer, 38KB);
// row/col means are computed during/from staging; all other phases stream
// fp32 x from global (L3-resident per block). LDS ~52KB -> 2 blocks/CU.

typedef short bf16x8 __attribute__((ext_vector_type(8)));
typedef float f32x4 __attribute__((ext_vector_type(4)));
typedef unsigned int u32x4 __attribute__((ext_vector_type(4)));

__device__ __forceinline__ unsigned short f2bf(float f) {
    union { float f; unsigned int u; } v; v.f = f;
    unsigned int u = v.u;
    u += 0x7fffu + ((u >> 16) & 1u);          // RNE
    return (unsigned short)(u >> 16);
}
__device__ __forceinline__ float bf2f(unsigned short h) {
    union { unsigned int u; float f; } v; v.u = ((unsigned int)h) << 16;
    return v.f;
}
__device__ __forceinline__ float sigm(float v) { return 1.0f / (1.0f + __expf(-v)); }

// chunk LDS layout: [lr 0..17][blk 0..1][w1 0..65][8ch] bf16 (ushort units)
#define CIDX(lr, w1, c) ((((lr)*2 + ((c)>>3))*66 + (w1))*8 + ((c)&7))

__global__ __launch_bounds__(512, 4) void ema_fused(
    const float* __restrict__ x,
    const float* __restrict__ w1, const float* __restrict__ b1,
    const float* __restrict__ wh, const float* __restrict__ bh,
    const float* __restrict__ ww, const float* __restrict__ bw,
    const float* __restrict__ w3, const float* __restrict__ b3,
    const float* __restrict__ gamma, const float* __restrict__ beta,
    float* __restrict__ out)
{
    const int n    = blockIdx.x;
    const int tid  = threadIdx.x;
    const int lane = tid & 63;
    const int wv   = tid >> 6;       // wave 0..7
    const int qd   = lane >> 4;      // quad 0..3
    const int col  = lane & 15;

    const float* xg = x + (size_t)n * 65536;
    unsigned int* ob = (unsigned int*)out + (size_t)n * 65536;   // uint view (x3 scratch + final out)

    __shared__ __align__(16) unsigned short sT[19008];   // 38016B chunk buf; aliased as float colScr after conv
    __shared__ __align__(16) float sG[2048];             // means -> y2 -> gates: ah[c*64+h], aw[1024+c*64+w]
    __shared__ float sRowP[1024];                        // per-chunk rowsum partials [(rr*2+chalf)*4+wq]*8+j
    __shared__ float sRedA[128], sRedB[128];
    __shared__ float sS1[16], sSQ[16], sMn[16], sMx[16], sM3[16], sS3[16];
    __shared__ float sA[16], sB1[16], sQ1[16], sQ3[16];
    __shared__ float sScal[2];

    // ---- init: zero rowsum accumulators (sG[0..1023]) + w-halo columns of sT ----
    sG[tid] = 0.f; sG[tid + 512] = 0.f;
    if (tid < 72) {
        int lr = tid >> 2, blk = (tid >> 1) & 1, w1 = (tid & 1) * 65;
        f32x4 zz = {0.f, 0.f, 0.f, 0.f};
        *(f32x4*)&sT[((lr*2 + blk)*66 + w1)*8] = zz;
    }

    // ---- conv weight fragments (same mapping as proven v1 kernel) ----
    bf16x8 afr[5];
    int offs[5];
    #pragma unroll
    for (int mm = 0; mm < 5; ++mm) {
        int t = 2*mm + (qd >> 1);
        #pragma unroll
        for (int j = 0; j < 8; ++j) {
            int i = ((qd & 1) << 3) + j;
            float v = (t <= 8) ? w3[(col*16 + i)*9 + t] : 0.0f;
            afr[mm][j] = (short)f2bf(v);
        }
        int tb = (t > 8) ? 8 : t;
        int dy = tb/3 - 1, dx = tb - (tb/3)*3 - 1;
        offs[mm] = dy*1056 + dx*8;          // lr coeff 1056 (=2*66*8), w1 coeff 8 (ushort units)
    }
    float b3v[4];
    #pragma unroll
    for (int r = 0; r < 4; ++r) b3v[r] = b3[qd*4 + r];

    float tmax[4] = {-1e30f,-1e30f,-1e30f,-1e30f};
    float tsum[4] = {0.f,0.f,0.f,0.f};
    float colacc[8] = {0.f,0.f,0.f,0.f,0.f,0.f,0.f,0.f};
    const int sblk = (tid >> 6) & 1;   // staging blk (fixed per thread)
    const int sw   = tid & 63;         // staging w   (fixed per thread; lane-consecutive -> coalesced)

    __syncthreads();

    // ================= Phase A/B/C x4: chunked stage + conv + means =================
    for (int c0 = 0; c0 < 4; ++c0) {
        // --- A: stage chunk (rows 16c0-1 .. 16c0+16) -> LDS bf16; colsum in regs ---
        #pragma unroll
        for (int k = 0; k < 5; ++k) {
            int t = k*512 + tid;
            if (t < 2304) {
                int lr = t >> 7;                    // 0..17
                int gr = (c0 << 4) + lr - 1;        // global row
                float v[8];
                if ((unsigned)gr < 64u) {
                    #pragma unroll
                    for (int j = 0; j < 8; ++j)
                        v[j] = xg[(sblk*8 + j)*4096 + gr*64 + sw];
                } else {
                    #pragma unroll
                    for (int j = 0; j < 8; ++j) v[j] = 0.f;
                }
                if ((unsigned)(lr - 1) < 16u) {     // interior rows only (each row counted once)
                    #pragma unroll
                    for (int j = 0; j < 8; ++j) colacc[j] += v[j];
                }
                u32x4 pk;
                #pragma unroll
                for (int m = 0; m < 4; ++m)
                    pk[m] = (unsigned int)f2bf(v[2*m]) | ((unsigned int)f2bf(v[2*m+1]) << 16);
                *(u32x4*)&sT[((lr*2 + sblk)*66 + (sw + 1))*8] = pk;
            }
        }
        __syncthreads();

        // --- B: rowsum partials (tid<128) + conv tiles (all threads) ---
        if (tid < 128) {
            int rr = tid >> 3, chalf = (tid >> 2) & 1, wq = tid & 3;
            float racc[8] = {0.f,0.f,0.f,0.f,0.f,0.f,0.f,0.f};
            #pragma unroll 4
            for (int wi = 0; wi < 16; ++wi) {
                const bf16x8 vv = *(const bf16x8*)&sT[CIDX(rr + 1, wq*16 + wi + 1, chalf*8)];
                #pragma unroll
                for (int j = 0; j < 8; ++j) racc[j] += bf2f((unsigned short)vv[j]);
            }
            #pragma unroll
            for (int j = 0; j < 8; ++j)
                sRowP[((rr*2 + chalf)*4 + wq)*8 + j] = racc[j];
        }
        #pragma unroll
        for (int k = 0; k < 8; ++k) {
            int tile = wv*8 + k;                    // 64 tiles per chunk
            int hl = tile >> 2, wq = tile & 3;
            int base = CIDX(hl + 1, wq*16 + col + 1, (qd & 1)*8);
            f32x4 acc = {0.f, 0.f, 0.f, 0.f};
            #pragma unroll
            for (int mm = 0; mm < 5; ++mm) {
                const bf16x8 bfr = *(const bf16x8*)&sT[base + offs[mm]];
                acc = __builtin_amdgcn_mfma_f32_16x16x32_bf16(afr[mm], bfr, acc, 0, 0, 0);
            }
            int p = ((c0 << 4) + hl)*64 + wq*16 + col;
            float xv4[4];
            #pragma unroll
            for (int r = 0; r < 4; ++r) {
                float v = acc[r] + b3v[r];
                float sv = v * sigm(v);
                xv4[r] = sv;
                tmax[r] = fmaxf(tmax[r], sv);
                tsum[r] += sv;
            }
            ob[(4*qd)*4096 + p]     = (unsigned int)f2bf(xv4[0]) | ((unsigned int)f2bf(xv4[1]) << 16);
            ob[(4*qd + 2)*4096 + p] = (unsigned int)f2bf(xv4[2]) | ((unsigned int)f2bf(xv4[3]) << 16);
        }
        __syncthreads();

        // --- C: rowsum reduce into sG[c*64+h] (disjoint rows per chunk; no sync needed after) ---
        if (tid < 256) {
            int c = tid & 15, rr = tid >> 4;
            int bse = (rr*2 + (c >> 3))*4;
            float s = sRowP[(bse + 0)*8 + (c & 7)] + sRowP[(bse + 1)*8 + (c & 7)]
                    + sRowP[(bse + 2)*8 + (c & 7)] + sRowP[(bse + 3)*8 + (c & 7)];
            sG[c*64 + (c0 << 4) + rr] += s;
        }
    }

    // ---- x3 stats wave-reduce (within 16-col groups, channels qd*4+r) ----
    #pragma unroll
    for (int m = 1; m < 16; m <<= 1) {
        #pragma unroll
        for (int r = 0; r < 4; ++r) {
            tmax[r] = fmaxf(tmax[r], __shfl_xor(tmax[r], m, 64));
            tsum[r] += __shfl_xor(tsum[r], m, 64);
        }
    }
    if (col == 0) {
        #pragma unroll
        for (int r = 0; r < 4; ++r) {
            sRedA[wv*16 + qd*4 + r] = tmax[r];
            sRedB[wv*16 + qd*4 + r] = tsum[r];
        }
    }
    // ---- colsum dump into sT alias (conv reads of sT are behind the B->C sync) ----
    {
        float* colScr = (float*)sT;
        f32x4 d0 = {colacc[0], colacc[1], colacc[2], colacc[3]};
        f32x4 d1 = {colacc[4], colacc[5], colacc[6], colacc[7]};
        *(f32x4*)&colScr[tid*8]     = d0;
        *(f32x4*)&colScr[tid*8 + 4] = d1;
    }
    __syncthreads();

    // ---- finalize means (scale 1/64) + x3 global max/sum ----
    {
        const float* colScr = (const float*)sT;
        #pragma unroll
        for (int s0 = 0; s0 < 2; ++s0) {
            int s = s0*512 + tid;
            int c = s >> 6, w = s & 63;
            int off = (c >> 3)*64 + w;
            float cs = colScr[(off      )*8 + (c & 7)] + colScr[(off + 128)*8 + (c & 7)]
                     + colScr[(off + 256)*8 + (c & 7)] + colScr[(off + 384)*8 + (c & 7)];
            sG[1024 + s] = cs * (1.0f/64.0f);       // col means (fp32-accurate)
            sG[s] *= (1.0f/64.0f);                  // row means
        }
    }
    if (tid < 16) {
        float mx = -1e30f, sm = 0.f;
        for (int v2 = 0; v2 < 8; ++v2) { mx = fmaxf(mx, sRedA[v2*16 + tid]); sm += sRedB[v2*16 + tid]; }
        sM3[tid] = mx; sS3[tid] = sm;
    }
    __syncthreads();

    // ---- Phase 3a: y2[o][q] = silu(W1 @ [xh;xw] + b1), q in [0,128) ----
    {
        float yv[4];
        #pragma unroll
        for (int j = 0; j < 4; ++j) {
            int tsk = tid + j*512;             // 0..2047
            int o = tsk & 15, q = tsk >> 4;
            float acc = b1[o];
            #pragma unroll
            for (int i = 0; i < 16; ++i)
                acc += w1[o*16 + i] * sG[((q>>6)<<10) + i*64 + (q & 63)];
            yv[j] = acc * sigm(acc);
        }
        __syncthreads();
        #pragma unroll
        for (int j = 0; j < 4; ++j) {
            int tsk = tid + j*512;
            int o = tsk & 15, q = tsk >> 4;
            sG[o*128 + q] = yv[j];
        }
    }
    __syncthreads();
    // ---- Phase 3b: a_h = sigmoid(Wh@y_h+bh), a_w = sigmoid(Ww@y_w+bw) ----
    {
        float av[4];
        #pragma unroll
        for (int j = 0; j < 4; ++j) {
            int tsk = tid + j*512;
            int kind = tsk >> 10;              // 0: ah, 1: aw
            int o = tsk & 15, pos = (tsk >> 4) & 63;
            const float* wm = kind ? ww : wh;
            float acc = kind ? bw[o] : bh[o];
            #pragma unroll
            for (int i = 0; i < 16; ++i)
                acc += wm[o*16 + i] * sG[i*128 + kind*64 + pos];
            av[j] = sigm(acc);
        }
        __syncthreads();
        #pragma unroll
        for (int j = 0; j < 4; ++j) {
            int tsk = tid + j*512;
            int kind = tsk >> 10, o = tsk & 15, pos = (tsk >> 4) & 63;
            sG[kind*1024 + o*64 + pos] = av[j];
        }
    }
    __syncthreads();

    // ---- Phase 5: x1 = x*ah*aw stats (wave-per-channel, fp32 x from global, coalesced) ----
    {
        #pragma unroll
        for (int cc = 0; cc < 2; ++cc) {
            const int c = wv*2 + cc;
            const int w0 = (lane & 15) * 4;
            const f32x4 aw4 = *(const f32x4*)&sG[1024 + c*64 + w0];
            float ps = 0.f, pq = 0.f, mn = 1e30f, mx = -1e30f;
            #pragma unroll 4
            for (int i = 0; i < 16; ++i) {
                const int p = i*256 + lane*4;
                const float ah = sG[c*64 + i*4 + (lane >> 4)];
                const f32x4 xv = *(const f32x4*)&xg[c*4096 + p];
                #pragma unroll
                for (int j = 0; j < 4; ++j) {
                    float x1 = xv[j] * ah * aw4[j];
                    ps += x1; pq = fmaf(x1, x1, pq);
                    mn = fminf(mn, x1); mx = fmaxf(mx, x1);
                }
            }
            #pragma unroll
            for (int m = 1; m < 64; m <<= 1) {
                ps += __shfl_xor(ps, m, 64);
                pq += __shfl_xor(pq, m, 64);
                mn = fminf(mn, __shfl_xor(mn, m, 64));
                mx = fmaxf(mx, __shfl_xor(mx, m, 64));
            }
            if (lane == 0) { sS1[c] = ps; sSQ[c] = pq; sMn[c] = mn; sMx[c] = mx; }
        }
    }
    __syncthreads();
    if (tid == 0) {
        float S = 0.f, Q = 0.f;
        for (int c = 0; c < 16; ++c) { S += sS1[c]; Q += sSQ[c]; }
        float mu = S * (1.0f/65536.0f);
        float var = Q * (1.0f/65536.0f) - mu*mu;
        sScal[0] = mu; sScal[1] = rsqrtf(var + 1e-5f);
    }
    __syncthreads();
    if (tid < 16) {
        float mu = sScal[0], rstd = sScal[1];
        float a  = gamma[tid] * rstd;
        float bb = beta[tid] - mu * a;                 // x1n = a*x1 + bb
        float m1 = (a >= 0.f) ? (a*sMx[tid] + bb) : (a*sMn[tid] + bb);
        sA[tid]  = a;
        sB1[tid] = bb - m1;                            // shifted logit = a*x1 + (bb-m1)
        sMn[tid] = a * (sS1[tid] * (1.0f/4096.0f)) + bb;   // v1
        sMx[tid] = sS3[tid] * (1.0f/4096.0f);              // v3
    }
    __syncthreads();

    // ---- Phase 7: Z1/Z3 exp-sums (fp32 x + bf16 x3 from global, float4) ----
    {
        float z1[16], z3[16];
        #pragma unroll
        for (int c = 0; c < 16; ++c) { z1[c] = 0.f; z3[c] = 0.f; }
        #pragma unroll
        for (int it = 0; it < 2; ++it) {
            const int p0 = it*2048 + tid*4;
            const int h  = p0 >> 6;
            const int w0 = (tid & 15)*4;
            #pragma unroll
            for (int c2 = 0; c2 < 8; ++c2) {
                const u32x4 xq = *(const u32x4*)&ob[(2*c2)*4096 + p0];
                #pragma unroll
                for (int hf = 0; hf < 2; ++hf) {
                    const int c = 2*c2 + hf;
                    const f32x4 xf  = *(const f32x4*)&xg[c*4096 + p0];
                    const f32x4 aw4 = *(const f32x4*)&sG[1024 + c*64 + w0];
                    const float tt = sG[c*64 + h] * sA[c];
                    const float bb = sB1[c];
                    const float m3 = sM3[c];
                    #pragma unroll
                    for (int j = 0; j < 4; ++j) {
                        z1[c] += __expf(fmaf(xf[j], tt * aw4[j], bb));
                        unsigned int uu = hf ? (xq[j] & 0xffff0000u) : (xq[j] << 16);
                        z3[c] += __expf(__uint_as_float(uu) - m3);
                    }
                }
            }
        }
        #pragma unroll
        for (int m = 1; m < 64; m <<= 1) {
            #pragma unroll
            for (int c = 0; c < 16; ++c) {
                z1[c] += __shfl_xor(z1[c], m, 64);
                z3[c] += __shfl_xor(z3[c], m, 64);
            }
        }
        if (lane == 0) {
            #pragma unroll
            for (int c = 0; c < 16; ++c) { sRedA[wv*16 + c] = z1[c]; sRedB[wv*16 + c] = z3[c]; }
        }
    }
    __syncthreads();
    if (tid < 16) {
        float a1 = 0.f, a3 = 0.f;
        for (int v2 = 0; v2 < 8; ++v2) { a1 += sRedA[v2*16 + tid]; a3 += sRedB[v2*16 + tid]; }
        sQ1[tid] = sMx[tid] / a1;      // v3 / Z1  (weights e1)
        sQ3[tid] = sMn[tid] / a3;      // v1 / Z3  (weights e3)
    }
    __syncthreads();

    // ---- Phase 8: s = sigmoid(sum_c q3*e3 + q1*e1); out = x_fp32 * s ----
    #pragma unroll
    for (int it = 0; it < 2; ++it) {
        const int p0 = it*2048 + tid*4;
        const int h  = p0 >> 6;
        const int w0 = (tid & 15)*4;
        f32x4 z = {0.f, 0.f, 0.f, 0.f};
        #pragma unroll
        for (int c2 = 0; c2 < 8; ++c2) {
            const u32x4 xq = *(const u32x4*)&ob[(2*c2)*4096 + p0];
            #pragma unroll
            for (int hf = 0; hf < 2; ++hf) {
                const int c = 2*c2 + hf;
                const f32x4 xf  = *(const f32x4*)&xg[c*4096 + p0];
                const f32x4 aw4 = *(const f32x4*)&sG[1024 + c*64 + w0];
                const float tt = sG[c*64 + h] * sA[c];
                const float bb = sB1[c];
                const float m3 = sM3[c];
                const float q1c = sQ1[c], q3c = sQ3[c];
                #pragma unroll
                for (int j = 0; j < 4; ++j) {
                    float e1 = __expf(fmaf(xf[j], tt * aw4[j], bb));
                    unsigned int uu = hf ? (xq[j] & 0xffff0000u) : (xq[j] << 16);
                    float e3 = __expf(__uint_as_float(uu) - m3);
                    z[j] = fmaf(q1c, e1, fmaf(q3c, e3, z[j]));
                }
            }
        }
        f32x4 s4;
        #pragma unroll
        for (int j = 0; j < 4; ++j) s4[j] = 1.0f / (1.0f + __expf(-z[j]));
        // own-pixel stores only (x3 slots for these pixels were read above; other threads' pixels disjoint)
        #pragma unroll
        for (int c = 0; c < 16; ++c) {
            const f32x4 xf = *(const f32x4*)&xg[c*4096 + p0];
            u32x4 o4;
            #pragma unroll
            for (int j = 0; j < 4; ++j) o4[j] = __float_as_uint(xf[j] * s4[j]);
            *(u32x4*)&ob[c*4096 + p0] = o4;
        }
    }
}

extern "C" void kernel_launch(void* const* d_in, const int* in_sizes, int n_in,
                              void* d_out, int out_size, void* d_ws, size_t ws_size,
                              hipStream_t stream) {
    const float* x     = (const float*)d_in[0];
    const float* w1    = (const float*)d_in[1];
    const float* b1    = (const float*)d_in[2];
    const float* wh    = (const float*)d_in[3];
    const float* bh    = (const float*)d_in[4];
    const float* ww    = (const float*)d_in[5];
    const float* bw    = (const float*)d_in[6];
    const float* w3    = (const float*)d_in[7];
    const float* b3    = (const float*)d_in[8];
    const float* gamma = (const float*)d_in[9];
    const float* beta  = (const float*)d_in[10];
    hipLaunchKernelGGL(ema_fused, dim3(1024), dim3(512), 0, stream,
                       x, w1, b1, wh, bh, ww, bw, w3, b3, gamma, beta, (float*)d_out);
}

// Round 2
// 745.908 us; speedup vs baseline: 1.8166x; 1.8166x over previous
//
#include <hip/hip_runtime.h>

// v3: one 1024-thread workgroup per group n (1024 groups of 16ch x 64x64).
// Keeps v1's LDS-resident bf16 x (minimal HBM traffic, proven numerics) but:
//  - 1024 threads -> 16 waves/CU (4/SIMD) instead of 8 (latency hiding x2)
//  - no x3 materialization: 3x3 conv recomputed by MFMA in each consuming
//    phase (stats / Z-sums / final) -> removes 384KB/block global round-trip
//  - x1 stats fused into the conv-stats pass (one fewer LDS sweep + barrier)

typedef short bf16x8 __attribute__((ext_vector_type(8)));
typedef short bf16x4 __attribute__((ext_vector_type(4)));
typedef float f32x4 __attribute__((ext_vector_type(4)));

__device__ __forceinline__ unsigned short f2bf(float f) {
    union { float f; unsigned int u; } v; v.f = f;
    unsigned int u = v.u;
    u += 0x7fffu + ((u >> 16) & 1u);          // RNE
    return (unsigned short)(u >> 16);
}
__device__ __forceinline__ float bf2f(unsigned short h) {
    union { unsigned int u; float f; } v; v.u = ((unsigned int)h) << 16;
    return v.f;
}
__device__ __forceinline__ float sigm(float v) { return 1.0f / (1.0f + __expf(-v)); }

// LDS x layout: [h1][blk][w1][8ch] bf16; blk = c>>3. (identical to proven v1)
#define XIDX(h1,w1,c) ((((h1)*2 + ((c)>>3))*66 + (w1))*8 + ((c)&7))

__global__ __launch_bounds__(1024) void ema_fused(
    const float* __restrict__ x,
    const float* __restrict__ w1, const float* __restrict__ b1,
    const float* __restrict__ wh, const float* __restrict__ bh,
    const float* __restrict__ ww, const float* __restrict__ bw,
    const float* __restrict__ w3, const float* __restrict__ b3,
    const float* __restrict__ gamma, const float* __restrict__ beta,
    float* __restrict__ out)
{
    const int n    = blockIdx.x;
    const int tid  = threadIdx.x;
    const int lane = tid & 63;
    const int wv   = tid >> 6;       // wave 0..15
    const int qd   = lane >> 4;      // quad 0..3
    const int col  = lane & 15;

    const float* xg = x + (size_t)n * 65536;
    float* ob = out + (size_t)n * 65536;

    __shared__ __align__(16) unsigned short sX[69696];   // 139392 B padded bf16 x
    __shared__ __align__(16) float sG[2048];             // means -> y2 -> gates: ah[c*64+h], aw[1024+c*64+w]
    __shared__ float sRedA[256], sRedB[256], sRedC[256], sRedD[256], sRedE[256], sRedF[256];
    __shared__ float sS1[16], sSQ[16], sMn[16], sMx[16], sM3[16], sS3[16];
    __shared__ float sA[16], sB1[16], sQ1[16], sQ3[16];
    __shared__ float sScal[2];

    // ---- Phase 1: zero-pad + stage x -> LDS bf16 ----
    for (int i = tid; i < 34848; i += 1024) ((unsigned int*)sX)[i] = 0u;
    __syncthreads();
    for (int e = tid; e < 32768; e += 1024) {
        int c2 = e & 7, w = (e >> 3) & 63, r = e >> 9;
        float v0 = xg[(2*c2)*4096 + r*64 + w];
        float v1 = xg[(2*c2+1)*4096 + r*64 + w];
        unsigned int pk = (unsigned int)f2bf(v0) | ((unsigned int)f2bf(v1) << 16);
        ((unsigned int*)sX)[XIDX(r+1, w+1, 2*c2) >> 1] = pk;
    }

    // ---- conv weight fragments (proven v1 mapping; global loads overlap barrier) ----
    bf16x8 afr[5];
    int offs[5];
    #pragma unroll
    for (int mm = 0; mm < 5; ++mm) {
        int t = 2*mm + (qd >> 1);
        #pragma unroll
        for (int j = 0; j < 8; ++j) {
            int i = ((qd & 1) << 3) + j;
            float v = (t <= 8) ? w3[(col*16 + i)*9 + t] : 0.0f;
            afr[mm][j] = (short)f2bf(v);
        }
        int tb = (t > 8) ? 8 : t;
        int dy = tb/3 - 1, dx = tb - (tb/3)*3 - 1;
        offs[mm] = dy*1056 + dx*8;          // h1 coeff 1056, w1 coeff 8 (ushort units)
    }
    float b3v[4];
    #pragma unroll
    for (int r = 0; r < 4; ++r) b3v[r] = b3[qd*4 + r];
    __syncthreads();

    // ---- Phase 2: row means (x_h) and col means (x_w); 512 threads, 32 iters each ----
    if (tid < 512) {
        int half = tid & 1;
        int part = (tid >> 1) & 1;
        int idx  = tid >> 2;          // 0..127
        int isCol = idx >> 6;         // 0: mean over w at r=idx ; 1: mean over h at w=idx-64
        int rc = idx & 63;
        float acc[8] = {0,0,0,0,0,0,0,0};
        for (int t = part*32; t < part*32 + 32; ++t) {
            int hh = isCol ? (t + 1) : (rc + 1);
            int wwi = isCol ? (rc + 1) : (t + 1);
            const bf16x8 v = *(const bf16x8*)&sX[XIDX(hh, wwi, half*8)];
            #pragma unroll
            for (int j = 0; j < 8; ++j) acc[j] += bf2f((unsigned short)v[j]);
        }
        #pragma unroll
        for (int j = 0; j < 8; ++j) acc[j] += __shfl_xor(acc[j], 2, 64);
        if (part == 0) {
            #pragma unroll
            for (int j = 0; j < 8; ++j)
                sG[isCol*1024 + (half*8+j)*64 + rc] = acc[j] * (1.0f/64.0f);
        }
    }
    __syncthreads();

    // ---- Phase 3a: y2[o][q] = silu(W1 @ [xh;xw] + b1), q in [0,128) ----
    {
        float yv[2];
        #pragma unroll
        for (int j = 0; j < 2; ++j) {
            int tsk = tid + j*1024;            // 0..2047
            int o = tsk & 15, q = tsk >> 4;
            float acc = b1[o];
            #pragma unroll
            for (int i = 0; i < 16; ++i)
                acc += w1[o*16 + i] * sG[((q>>6)<<10) + i*64 + (q & 63)];
            yv[j] = acc * sigm(acc);
        }
        __syncthreads();
        #pragma unroll
        for (int j = 0; j < 2; ++j) {
            int tsk = tid + j*1024;
            int o = tsk & 15, q = tsk >> 4;
            sG[o*128 + q] = yv[j];
        }
    }
    __syncthreads();
    // ---- Phase 3b: a_h = sigmoid(Wh@y_h+bh), a_w = sigmoid(Ww@y_w+bw) ----
    {
        float av[2];
        #pragma unroll
        for (int j = 0; j < 2; ++j) {
            int tsk = tid + j*1024;
            int kind = tsk >> 10;              // 0: ah, 1: aw
            int o = tsk & 15, pos = (tsk >> 4) & 63;
            const float* wm = kind ? ww : wh;
            float acc = kind ? bw[o] : bh[o];
            #pragma unroll
            for (int i = 0; i < 16; ++i)
                acc += wm[o*16 + i] * sG[i*128 + kind*64 + pos];
            av[j] = sigm(acc);
        }
        __syncthreads();
        #pragma unroll
        for (int j = 0; j < 2; ++j) {
            int tsk = tid + j*1024;
            int kind = tsk >> 10, o = tsk & 15, pos = (tsk >> 4) & 63;
            sG[kind*1024 + o*64 + pos] = av[j];
        }
    }
    __syncthreads();

    // ---- Phase 4: conv stats (x3 max/sum) + x1 stats (sum/sq/min/max), fused ----
    {
        float tmax[4] = {-1e30f,-1e30f,-1e30f,-1e30f};
        float tsum[4] = {0.f,0.f,0.f,0.f};
        float s1[4] = {0.f,0.f,0.f,0.f}, q1[4] = {0.f,0.f,0.f,0.f};
        float mn[4] = {1e30f,1e30f,1e30f,1e30f}, mx[4] = {-1e30f,-1e30f,-1e30f,-1e30f};
        for (int k = 0; k < 16; ++k) {
            int tile = wv*16 + k;               // 0..255
            int hl = tile >> 2, wq = tile & 3;
            int w = wq*16 + col;
            int base = XIDX(hl+1, w+1, (qd & 1)*8);
            f32x4 acc = {0.f, 0.f, 0.f, 0.f};
            #pragma unroll
            for (int mm = 0; mm < 5; ++mm) {
                const bf16x8 bfr = *(const bf16x8*)&sX[base + offs[mm]];
                acc = __builtin_amdgcn_mfma_f32_16x16x32_bf16(afr[mm], bfr, acc, 0, 0, 0);
            }
            const bf16x4 xv4 = *(const bf16x4*)&sX[XIDX(hl+1, w+1, qd*4)];
            #pragma unroll
            for (int r = 0; r < 4; ++r) {
                float v = acc[r] + b3v[r];
                float sv = v * sigm(v);
                tmax[r] = fmaxf(tmax[r], sv); tsum[r] += sv;
                int c = qd*4 + r;
                float g = sG[c*64 + hl] * sG[1024 + c*64 + w];
                float x1v = bf2f((unsigned short)xv4[r]) * g;
                s1[r] += x1v; q1[r] = fmaf(x1v, x1v, q1[r]);
                mn[r] = fminf(mn[r], x1v); mx[r] = fmaxf(mx[r], x1v);
            }
        }
        #pragma unroll
        for (int m = 1; m < 16; m <<= 1) {
            #pragma unroll
            for (int r = 0; r < 4; ++r) {
                tmax[r] = fmaxf(tmax[r], __shfl_xor(tmax[r], m, 64));
                tsum[r] += __shfl_xor(tsum[r], m, 64);
                s1[r] += __shfl_xor(s1[r], m, 64);
                q1[r] += __shfl_xor(q1[r], m, 64);
                mn[r] = fminf(mn[r], __shfl_xor(mn[r], m, 64));
                mx[r] = fmaxf(mx[r], __shfl_xor(mx[r], m, 64));
            }
        }
        if (col == 0) {
            #pragma unroll
            for (int r = 0; r < 4; ++r) {
                int s = wv*16 + qd*4 + r;
                sRedA[s] = tmax[r]; sRedB[s] = tsum[r];
                sRedC[s] = s1[r];   sRedD[s] = q1[r];
                sRedE[s] = mn[r];   sRedF[s] = mx[r];
            }
        }
    }
    __syncthreads();
    if (tid < 16) {
        float m3 = -1e30f, sm3 = 0.f, s = 0.f, q = 0.f, mn = 1e30f, mx = -1e30f;
        for (int v2 = 0; v2 < 16; ++v2) {
            m3 = fmaxf(m3, sRedA[v2*16 + tid]); sm3 += sRedB[v2*16 + tid];
            s += sRedC[v2*16 + tid]; q += sRedD[v2*16 + tid];
            mn = fminf(mn, sRedE[v2*16 + tid]); mx = fmaxf(mx, sRedF[v2*16 + tid]);
        }
        sM3[tid] = m3; sS3[tid] = sm3;
        sS1[tid] = s; sSQ[tid] = q; sMn[tid] = mn; sMx[tid] = mx;
    }
    __syncthreads();
    if (tid == 0) {
        float S = 0.f, Q = 0.f;
        for (int c = 0; c < 16; ++c) { S += sS1[c]; Q += sSQ[c]; }
        float mu = S * (1.0f/65536.0f);
        float var = Q * (1.0f/65536.0f) - mu*mu;
        sScal[0] = mu; sScal[1] = rsqrtf(var + 1e-5f);
    }
    __syncthreads();
    if (tid < 16) {
        float mu = sScal[0], rstd = sScal[1];
        float a  = gamma[tid] * rstd;
        float bb = beta[tid] - mu * a;                 // x1n = a*x1 + bb
        float m1 = (a >= 0.f) ? (a*sMx[tid] + bb) : (a*sMn[tid] + bb);
        sA[tid]  = a;
        sB1[tid] = bb - m1;                            // shifted logit = a*x1 + (bb-m1)
        sMn[tid] = a * (sS1[tid] * (1.0f/4096.0f)) + bb;   // v1
        sMx[tid] = sS3[tid] * (1.0f/4096.0f);              // v3
    }
    __syncthreads();

    // ---- Phase 7: Z1/Z3 exp-sums (conv recomputed; x from LDS bf16) ----
    {
        float aC[4], bC[4], m3C[4];
        #pragma unroll
        for (int r = 0; r < 4; ++r) {
            int c = qd*4 + r;
            aC[r] = sA[c]; bC[r] = sB1[c]; m3C[r] = sM3[c];
        }
        float z1p[4] = {0.f,0.f,0.f,0.f}, z3p[4] = {0.f,0.f,0.f,0.f};
        for (int k = 0; k < 16; ++k) {
            int tile = wv*16 + k;
            int hl = tile >> 2, wq = tile & 3;
            int w = wq*16 + col;
            int base = XIDX(hl+1, w+1, (qd & 1)*8);
            f32x4 acc = {0.f, 0.f, 0.f, 0.f};
            #pragma unroll
            for (int mm = 0; mm < 5; ++mm) {
                const bf16x8 bfr = *(const bf16x8*)&sX[base + offs[mm]];
                acc = __builtin_amdgcn_mfma_f32_16x16x32_bf16(afr[mm], bfr, acc, 0, 0, 0);
            }
            const bf16x4 xv4 = *(const bf16x4*)&sX[XIDX(hl+1, w+1, qd*4)];
            #pragma unroll
            for (int r = 0; r < 4; ++r) {
                float v = acc[r] + b3v[r];
                float sv = v * sigm(v);
                z3p[r] += __expf(sv - m3C[r]);
                int c = qd*4 + r;
                float g = sG[c*64 + hl] * sG[1024 + c*64 + w];
                z1p[r] += __expf(fmaf(bf2f((unsigned short)xv4[r]), g*aC[r], bC[r]));
            }
        }
        #pragma unroll
        for (int m = 1; m < 16; m <<= 1) {
            #pragma unroll
            for (int r = 0; r < 4; ++r) {
                z1p[r] += __shfl_xor(z1p[r], m, 64);
                z3p[r] += __shfl_xor(z3p[r], m, 64);
            }
        }
        if (col == 0) {
            #pragma unroll
            for (int r = 0; r < 4; ++r) {
                sRedA[wv*16 + qd*4 + r] = z1p[r];
                sRedB[wv*16 + qd*4 + r] = z3p[r];
            }
        }
    }
    __syncthreads();
    if (tid < 16) {
        float a1 = 0.f, a3 = 0.f;
        for (int v2 = 0; v2 < 16; ++v2) { a1 += sRedA[v2*16 + tid]; a3 += sRedB[v2*16 + tid]; }
        sQ1[tid] = sMx[tid] / a1;      // v3 / Z1  (weights e1)
        sQ3[tid] = sMn[tid] / a3;      // v1 / Z3  (weights e3)
    }
    __syncthreads();

    // ---- Phase 8: s = sigmoid(sum_c q3*e3 + q1*e1); out = x_fp32 * s ----
    {
        float aC[4], bC[4], m3C[4], q1C[4], q3C[4];
        #pragma unroll
        for (int r = 0; r < 4; ++r) {
            int c = qd*4 + r;
            aC[r] = sA[c]; bC[r] = sB1[c]; m3C[r] = sM3[c];
            q1C[r] = sQ1[c]; q3C[r] = sQ3[c];
        }
        for (int k = 0; k < 16; ++k) {
            int tile = wv*16 + k;
            int hl = tile >> 2, wq = tile & 3;
            int w = wq*16 + col;
            int p = hl*64 + w;
            int base = XIDX(hl+1, w+1, (qd & 1)*8);
            f32x4 acc = {0.f, 0.f, 0.f, 0.f};
            #pragma unroll
            for (int mm = 0; mm < 5; ++mm) {
                const bf16x8 bfr = *(const bf16x8*)&sX[base + offs[mm]];
                acc = __builtin_amdgcn_mfma_f32_16x16x32_bf16(afr[mm], bfr, acc, 0, 0, 0);
            }
            const bf16x4 xv4 = *(const bf16x4*)&sX[XIDX(hl+1, w+1, qd*4)];
            float xf[4];
            #pragma unroll
            for (int r = 0; r < 4; ++r) xf[r] = xg[(qd*4 + r)*4096 + p];
            float zp = 0.f;
            #pragma unroll
            for (int r = 0; r < 4; ++r) {
                float v = acc[r] + b3v[r];
                float sv = v * sigm(v);
                float e3 = __expf(sv - m3C[r]);
                int c = qd*4 + r;
                float g = sG[c*64 + hl] * sG[1024 + c*64 + w];
                float e1 = __expf(fmaf(bf2f((unsigned short)xv4[r]), g*aC[r], bC[r]));
                zp = fmaf(q3C[r], e3, fmaf(q1C[r], e1, zp));
            }
            zp += __shfl_xor(zp, 16, 64);
            zp += __shfl_xor(zp, 32, 64);
            float s = 1.0f / (1.0f + __expf(-zp));
            #pragma unroll
            for (int r = 0; r < 4; ++r)
                ob[(qd*4 + r)*4096 + p] = xf[r] * s;
        }
    }
}

extern "C" void kernel_launch(void* const* d_in, const int* in_sizes, int n_in,
                              void* d_out, int out_size, void* d_ws, size_t ws_size,
                              hipStream_t stream) {
    const float* x     = (const float*)d_in[0];
    const float* w1    = (const float*)d_in[1];
    const float* b1    = (const float*)d_in[2];
    const float* wh    = (const float*)d_in[3];
    const float* bh    = (const float*)d_in[4];
    const float* ww    = (const float*)d_in[5];
    const float* bw    = (const float*)d_in[6];
    const float* w3    = (const float*)d_in[7];
    const float* b3    = (const float*)d_in[8];
    const float* gamma = (const float*)d_in[9];
    const float* beta  = (const float*)d_in[10];
    hipLaunchKernelGGL(ema_fused, dim3(1024), dim3(1024), 0, stream,
                       x, w1, b1, wh, bh, ww, bw, w3, b3, gamma, beta, (float*)d_out);
}

// Round 3
// 726.724 us; speedup vs baseline: 1.8646x; 1.0264x over previous
//
#include <hip/hip_runtime.h>

// v4: one 1024-thread workgroup per group n (1024 groups of 16ch x 64x64).
// Structure: stage x->LDS bf16 | means | gating | pass A: x1 sum/sumsq (no conv,
// no-max softmax needs no min/max) | pass B: SINGLE conv sweep in 16-row chunks:
// conv+silu -> x3, accumulate Z3,S3 and Z1 (e1 from bf16 x), then write bf16 x3
// IN-PLACE over dead x rows (slot h-2; rows 0,1 -> side buffer) | pass C: final
// s from LDS x3 + fp32 global x (rounded to bf16 for logit consistency), out.

typedef short bf16x8 __attribute__((ext_vector_type(8)));
typedef short bf16x4 __attribute__((ext_vector_type(4)));
typedef float f32x4 __attribute__((ext_vector_type(4)));
typedef unsigned int u32x2 __attribute__((ext_vector_type(2)));

__device__ __forceinline__ unsigned short f2bf(float f) {
    union { float f; unsigned int u; } v; v.f = f;
    unsigned int u = v.u;
    u += 0x7fffu + ((u >> 16) & 1u);          // RNE
    return (unsigned short)(u >> 16);
}
__device__ __forceinline__ float bf2f(unsigned short h) {
    union { unsigned int u; float f; } v; v.u = ((unsigned int)h) << 16;
    return v.f;
}
__device__ __forceinline__ float sigm(float v) { return 1.0f / (1.0f + __expf(-v)); }

// LDS x layout: [h1][blk][w1][8ch] bf16; blk = c>>3. (identical to proven v1/v3)
#define XIDX(h1,w1,c) ((((h1)*2 + ((c)>>3))*66 + (w1))*8 + ((c)&7))

__global__ __launch_bounds__(1024) void ema_fused(
    const float* __restrict__ x,
    const float* __restrict__ w1, const float* __restrict__ b1,
    const float* __restrict__ wh, const float* __restrict__ bh,
    const float* __restrict__ ww, const float* __restrict__ bw,
    const float* __restrict__ w3, const float* __restrict__ b3,
    const float* __restrict__ gamma, const float* __restrict__ beta,
    float* __restrict__ out)
{
    const int n    = blockIdx.x;
    const int tid  = threadIdx.x;
    const int lane = tid & 63;
    const int wv   = tid >> 6;       // wave 0..15
    const int qd   = lane >> 4;      // quad 0..3
    const int col  = lane & 15;

    const float* xg = x + (size_t)n * 65536;
    float* ob = out + (size_t)n * 65536;

    __shared__ __align__(16) unsigned short sX[69696];   // 139392 B padded bf16 x (later: x3 in slots h-2)
    __shared__ __align__(16) unsigned short sXtra[2048]; // x3 rows 0,1: [h][w][16c] bf16
    __shared__ __align__(16) float sG[2048];             // means -> y2 -> gates: ah[c*64+h], aw[1024+c*64+w]
    __shared__ float sRedA[256], sRedB[256], sRedC[256];
    __shared__ float sS1[16], sSQ[16], sV1[16];
    __shared__ float sA[16], sB1[16], sQ1[16], sQ3[16];
    __shared__ float sScal[2];

    // ---- Phase 1: zero-pad + stage x -> LDS bf16 ----
    for (int i = tid; i < 34848; i += 1024) ((unsigned int*)sX)[i] = 0u;
    __syncthreads();
    for (int e = tid; e < 32768; e += 1024) {
        int c2 = e & 7, w = (e >> 3) & 63, r = e >> 9;
        float v0 = xg[(2*c2)*4096 + r*64 + w];
        float v1 = xg[(2*c2+1)*4096 + r*64 + w];
        unsigned int pk = (unsigned int)f2bf(v0) | ((unsigned int)f2bf(v1) << 16);
        ((unsigned int*)sX)[XIDX(r+1, w+1, 2*c2) >> 1] = pk;
    }

    // ---- conv weight fragments (proven v1 mapping; global loads overlap barrier) ----
    bf16x8 afr[5];
    int offs[5];
    #pragma unroll
    for (int mm = 0; mm < 5; ++mm) {
        int t = 2*mm + (qd >> 1);
        #pragma unroll
        for (int j = 0; j < 8; ++j) {
            int i = ((qd & 1) << 3) + j;
            float v = (t <= 8) ? w3[(col*16 + i)*9 + t] : 0.0f;
            afr[mm][j] = (short)f2bf(v);
        }
        int tb = (t > 8) ? 8 : t;
        int dy = tb/3 - 1, dx = tb - (tb/3)*3 - 1;
        offs[mm] = dy*1056 + dx*8;          // h1 coeff 1056, w1 coeff 8 (ushort units)
    }
    float b3v[4];
    #pragma unroll
    for (int r = 0; r < 4; ++r) b3v[r] = b3[qd*4 + r];
    __syncthreads();

    // ---- Phase 2: row means (x_h) and col means (x_w) ----
    if (tid < 512) {
        int half = tid & 1;
        int part = (tid >> 1) & 1;
        int idx  = tid >> 2;          // 0..127
        int isCol = idx >> 6;         // 0: mean over w at r=idx ; 1: mean over h at w=idx-64
        int rc = idx & 63;
        float acc[8] = {0,0,0,0,0,0,0,0};
        for (int t = part*32; t < part*32 + 32; ++t) {
            int hh = isCol ? (t + 1) : (rc + 1);
            int wwi = isCol ? (rc + 1) : (t + 1);
            const bf16x8 v = *(const bf16x8*)&sX[XIDX(hh, wwi, half*8)];
            #pragma unroll
            for (int j = 0; j < 8; ++j) acc[j] += bf2f((unsigned short)v[j]);
        }
        #pragma unroll
        for (int j = 0; j < 8; ++j) acc[j] += __shfl_xor(acc[j], 2, 64);
        if (part == 0) {
            #pragma unroll
            for (int j = 0; j < 8; ++j)
                sG[isCol*1024 + (half*8+j)*64 + rc] = acc[j] * (1.0f/64.0f);
        }
    }
    __syncthreads();

    // ---- Phase 3a: y2[o][q] = silu(W1 @ [xh;xw] + b1), q in [0,128) ----
    {
        float yv[2];
        #pragma unroll
        for (int j = 0; j < 2; ++j) {
            int tsk = tid + j*1024;            // 0..2047
            int o = tsk & 15, q = tsk >> 4;
            float acc = b1[o];
            #pragma unroll
            for (int i = 0; i < 16; ++i)
                acc += w1[o*16 + i] * sG[((q>>6)<<10) + i*64 + (q & 63)];
            yv[j] = acc * sigm(acc);
        }
        __syncthreads();
        #pragma unroll
        for (int j = 0; j < 2; ++j) {
            int tsk = tid + j*1024;
            int o = tsk & 15, q = tsk >> 4;
            sG[o*128 + q] = yv[j];
        }
    }
    __syncthreads();
    // ---- Phase 3b: a_h = sigmoid(Wh@y_h+bh), a_w = sigmoid(Ww@y_w+bw) ----
    {
        float av[2];
        #pragma unroll
        for (int j = 0; j < 2; ++j) {
            int tsk = tid + j*1024;
            int kind = tsk >> 10;              // 0: ah, 1: aw
            int o = tsk & 15, pos = (tsk >> 4) & 63;
            const float* wm = kind ? ww : wh;
            float acc = kind ? bw[o] : bh[o];
            #pragma unroll
            for (int i = 0; i < 16; ++i)
                acc += wm[o*16 + i] * sG[i*128 + kind*64 + pos];
            av[j] = sigm(acc);
        }
        __syncthreads();
        #pragma unroll
        for (int j = 0; j < 2; ++j) {
            int tsk = tid + j*1024;
            int kind = tsk >> 10, o = tsk & 15, pos = (tsk >> 4) & 63;
            sG[kind*1024 + o*64 + pos] = av[j];
        }
    }
    __syncthreads();

    // ---- Pass A: x1 = x*ah*aw, per-channel sum + sumsq only (no-max softmax) ----
    {
        float s1[4] = {0.f,0.f,0.f,0.f}, q1[4] = {0.f,0.f,0.f,0.f};
        for (int k = 0; k < 16; ++k) {
            int tile = wv*16 + k;               // 0..255
            int hl = tile >> 2, wq = tile & 3;
            int w = wq*16 + col;
            const bf16x4 xv4 = *(const bf16x4*)&sX[XIDX(hl+1, w+1, qd*4)];
            #pragma unroll
            for (int r = 0; r < 4; ++r) {
                int c = qd*4 + r;
                float g = sG[c*64 + hl] * sG[1024 + c*64 + w];
                float x1v = bf2f((unsigned short)xv4[r]) * g;
                s1[r] += x1v; q1[r] = fmaf(x1v, x1v, q1[r]);
            }
        }
        #pragma unroll
        for (int m = 1; m < 16; m <<= 1) {
            #pragma unroll
            for (int r = 0; r < 4; ++r) {
                s1[r] += __shfl_xor(s1[r], m, 64);
                q1[r] += __shfl_xor(q1[r], m, 64);
            }
        }
        if (col == 0) {
            #pragma unroll
            for (int r = 0; r < 4; ++r) {
                sRedA[wv*16 + qd*4 + r] = s1[r];
                sRedB[wv*16 + qd*4 + r] = q1[r];
            }
        }
    }
    __syncthreads();
    if (tid < 16) {
        float s = 0.f, q = 0.f;
        for (int v2 = 0; v2 < 16; ++v2) { s += sRedA[v2*16 + tid]; q += sRedB[v2*16 + tid]; }
        sS1[tid] = s; sSQ[tid] = q;
    }
    __syncthreads();
    if (tid == 0) {
        float S = 0.f, Q = 0.f;
        for (int c = 0; c < 16; ++c) { S += sS1[c]; Q += sSQ[c]; }
        float mu = S * (1.0f/65536.0f);
        float var = Q * (1.0f/65536.0f) - mu*mu;
        sScal[0] = mu; sScal[1] = rsqrtf(var + 1e-5f);
    }
    __syncthreads();
    if (tid < 16) {
        float mu = sScal[0], rstd = sScal[1];
        float a  = gamma[tid] * rstd;
        float bb = beta[tid] - mu * a;                 // logit = a*x1 + bb (no max shift)
        sA[tid]  = a;
        sB1[tid] = bb;
        sV1[tid] = fmaf(a, sS1[tid] * (1.0f/4096.0f), bb);   // v1
    }
    __syncthreads();

    // ---- Pass B: single conv sweep, 4 chunks of 16 rows; Z1/Z3/S3; x3 -> LDS in-place ----
    {
        float aC[4], bC[4];
        #pragma unroll
        for (int r = 0; r < 4; ++r) { int c = qd*4 + r; aC[r] = sA[c]; bC[r] = sB1[c]; }
        float z1p[4] = {0.f,0.f,0.f,0.f}, z3p[4] = {0.f,0.f,0.f,0.f}, s3p[4] = {0.f,0.f,0.f,0.f};

        for (int c0 = 0; c0 < 4; ++c0) {
            unsigned int x3p[4][2];
            #pragma unroll
            for (int k = 0; k < 4; ++k) {
                int idx = wv*4 + k;             // 0..63 tiles in chunk
                int hl = idx >> 2, wq = idx & 3;
                int h = c0*16 + hl;
                int w = wq*16 + col;
                int base = XIDX(h+1, w+1, (qd & 1)*8);
                f32x4 acc = {0.f, 0.f, 0.f, 0.f};
                #pragma unroll
                for (int mm = 0; mm < 5; ++mm) {
                    const bf16x8 bfr = *(const bf16x8*)&sX[base + offs[mm]];
                    acc = __builtin_amdgcn_mfma_f32_16x16x32_bf16(afr[mm], bfr, acc, 0, 0, 0);
                }
                const bf16x4 xv4 = *(const bf16x4*)&sX[XIDX(h+1, w+1, qd*4)];
                unsigned short sb[4];
                #pragma unroll
                for (int r = 0; r < 4; ++r) {
                    float v = acc[r] + b3v[r];
                    float sv = v * sigm(v);
                    s3p[r] += sv;                          // v3 accumulates fp32 (matches ref path)
                    sb[r] = f2bf(sv);
                    z3p[r] += __expf(bf2f(sb[r]));         // denominator from the bf16-rounded value
                    int c = qd*4 + r;
                    float g = sG[c*64 + h] * sG[1024 + c*64 + w];
                    z1p[r] += __expf(fmaf(bf2f((unsigned short)xv4[r]), g*aC[r], bC[r]));
                }
                x3p[k][0] = (unsigned int)sb[0] | ((unsigned int)sb[1] << 16);
                x3p[k][1] = (unsigned int)sb[2] | ((unsigned int)sb[3] << 16);
            }
            __syncthreads();    // all chunk reads done -> safe to overwrite dead rows
            #pragma unroll
            for (int k = 0; k < 4; ++k) {
                int idx = wv*4 + k;
                int hl = idx >> 2, wq = idx & 3;
                int h = c0*16 + hl;
                int w = wq*16 + col;
                u32x2 pk = {x3p[k][0], x3p[k][1]};
                if (h >= 2) *(u32x2*)&sX[XIDX(h-1, w+1, qd*4)] = pk;   // slot row h-2 (h1 = h-1)
                else        *(u32x2*)&sXtra[(h*64 + w)*16 + qd*4] = pk;
            }
            // no barrier needed: next chunk reads rows >= 16c0+15, writes were <= 16c0+13
        }

        #pragma unroll
        for (int m = 1; m < 16; m <<= 1) {
            #pragma unroll
            for (int r = 0; r < 4; ++r) {
                z1p[r] += __shfl_xor(z1p[r], m, 64);
                z3p[r] += __shfl_xor(z3p[r], m, 64);
                s3p[r] += __shfl_xor(s3p[r], m, 64);
            }
        }
        if (col == 0) {
            #pragma unroll
            for (int r = 0; r < 4; ++r) {
                sRedA[wv*16 + qd*4 + r] = z1p[r];
                sRedB[wv*16 + qd*4 + r] = z3p[r];
                sRedC[wv*16 + qd*4 + r] = s3p[r];
            }
        }
    }
    __syncthreads();
    if (tid < 16) {
        float Z1 = 0.f, Z3 = 0.f, S3 = 0.f;
        for (int v2 = 0; v2 < 16; ++v2) {
            Z1 += sRedA[v2*16 + tid]; Z3 += sRedB[v2*16 + tid]; S3 += sRedC[v2*16 + tid];
        }
        sQ1[tid] = (S3 * (1.0f/4096.0f)) / Z1;   // v3 / Z1 (weights e1)
        sQ3[tid] = sV1[tid] / Z3;                // v1 / Z3 (weights e3)
    }
    __syncthreads();

    // ---- Pass C: s = sigmoid(sum_c q3*e3 + q1*e1); out = x_fp32 * s ----
    {
        float aC[4], bC[4], q1C[4], q3C[4];
        #pragma unroll
        for (int r = 0; r < 4; ++r) {
            int c = qd*4 + r;
            aC[r] = sA[c]; bC[r] = sB1[c]; q1C[r] = sQ1[c]; q3C[r] = sQ3[c];
        }
        for (int k = 0; k < 16; ++k) {
            int tile = wv*16 + k;
            int hl = tile >> 2, wq = tile & 3;
            int w = wq*16 + col;
            int p = hl*64 + w;
            bf16x4 x3v;
            if (hl >= 2) x3v = *(const bf16x4*)&sX[XIDX(hl-1, w+1, qd*4)];
            else         x3v = *(const bf16x4*)&sXtra[(hl*64 + w)*16 + qd*4];
            float xf[4];
            #pragma unroll
            for (int r = 0; r < 4; ++r) xf[r] = xg[(qd*4 + r)*4096 + p];
            float zp = 0.f;
            #pragma unroll
            for (int r = 0; r < 4; ++r) {
                float e3 = __expf(bf2f((unsigned short)x3v[r]));
                int c = qd*4 + r;
                float g = sG[c*64 + hl] * sG[1024 + c*64 + w];
                float xb = bf2f(f2bf(xf[r]));          // bf16-rounded: bit-identical logit to pass B
                float e1 = __expf(fmaf(xb, g*aC[r], bC[r]));
                zp = fmaf(q3C[r], e3, fmaf(q1C[r], e1, zp));
            }
            zp += __shfl_xor(zp, 16, 64);
            zp += __shfl_xor(zp, 32, 64);
            float s = 1.0f / (1.0f + __expf(-zp));
            #pragma unroll
            for (int r = 0; r < 4; ++r)
                ob[(qd*4 + r)*4096 + p] = xf[r] * s;
        }
    }
}

extern "C" void kernel_launch(void* const* d_in, const int* in_sizes, int n_in,
                              void* d_out, int out_size, void* d_ws, size_t ws_size,
                              hipStream_t stream) {
    const float* x     = (const float*)d_in[0];
    const float* w1    = (const float*)d_in[1];
    const float* b1    = (const float*)d_in[2];
    const float* wh    = (const float*)d_in[3];
    const float* bh    = (const float*)d_in[4];
    const float* ww    = (const float*)d_in[5];
    const float* bw    = (const float*)d_in[6];
    const float* w3    = (const float*)d_in[7];
    const float* b3    = (const float*)d_in[8];
    const float* gamma = (const float*)d_in[9];
    const float* beta  = (const float*)d_in[10];
    hipLaunchKernelGGL(ema_fused, dim3(1024), dim3(1024), 0, stream,
                       x, w1, b1, wh, bh, ww, bw, w3, b3, gamma, beta, (float*)d_out);
}